// Round 1
// baseline (247.267 us; speedup 1.0000x reference)
//
#include <hip/hip_runtime.h>
#include <math.h>

// FourierConv via DFT-as-GEMM on the MATRIX pipe.
// out[b,h,w,c] = Re(ifft2(fft2(x,255^2)*Ksum))[h+63,w+63] + bias; Ksum = sum_cout K.
// Half-spectrum q=0..127. Stages 2 (m->p), 4 (p->h), 5 (q->w real part) are bf16 MFMA
// GEMMs with SPLIT precision: a*b ~= aH*bH + aH*bL + aL*bH (rel err ~2^-17).
// Operand-fragment rule (verified): both MFMA operands use layout [entity=lane&15][k=quad*8+j];
// first arg's entity -> D row (quad*4+reg), second arg's entity -> D col (lane&15).
// stage4 computes D[q][h] (A=Z, B=T4) so its epilogue emits V directly in stage5's
// A-operand bf16 layout (a5) -- k-contiguous per lane. stage5 is a K=256 GEMM (2 p-segs
// folded into K; seg-sum is free in the accumulator) + (2S - v0)*1/N^2 + bias epilogue.

constexpr float PI2_OVER_N = 6.28318530717958647692f / 255.0f;
constexpr float INV_N2 = 1.0f / (255.0f * 255.0f);

typedef __attribute__((ext_vector_type(8))) short bf16x8;   // 8 bf16 = 4 VGPR
typedef __attribute__((ext_vector_type(4))) float f32x4;    // MFMA acc
#define MFMA16 __builtin_amdgcn_mfma_f32_16x16x32_bf16

__device__ __forceinline__ int remap_bc(int xidx) {
  int k = xidx & 7, j = xidx >> 3;
  return ((k >> 1) * 16) + ((k & 1) * 8) + j;   // b = k>>1, c = (k&1)*8 + j
}

__device__ __forceinline__ void cmul_update(float& tr, float& ti, float fr, float fi) {
  float ntr = tr * fr - ti * fi;
  ti = tr * fi + ti * fr;
  tr = ntr;
}

__device__ __forceinline__ unsigned short bf16h(float f) {
  unsigned u = __float_as_uint(f);
  return (unsigned short)((u + 0x7FFFu + ((u >> 16) & 1u)) >> 16);
}
__device__ __forceinline__ float bf16f(unsigned short h) {
  return __uint_as_float(((unsigned)h) << 16);
}

// ---------- ksum: S[r] = sum_cout kernel[r*16 .. r*16+16) ----------
// Coalesced variant: each wave owns a contiguous 4 KB chunk (64 rows). Lane l, step j
// loads float4 chunk[j*64+l] (1 KB/instr, lane-contiguous). That float4 is quarter
// (l&3) of row j*16+(l>>2); shfl_xor(1),(2) reduces within each 4-lane group, then
// lanes l%4==0 store 16 consecutive floats (one 64B line) per step.
__global__ __launch_bounds__(256) void ksum(
    const float* __restrict__ kr, const float* __restrict__ ki,
    float* __restrict__ Sr, float* __restrict__ Si) {
  const int nrows = 255 * 255 * 16;
  int lane = threadIdx.x & 63;
  int wave = threadIdx.x >> 6;
  int wrow0 = blockIdx.x * 256 + wave * 64;     // first row of this wave's chunk
  const float* src = (blockIdx.y == 0) ? kr : ki;
  float* dst = (blockIdx.y == 0) ? Sr : Si;
  const float4* s4 = (const float4*)src + (size_t)wrow0 * 4;
#pragma unroll
  for (int j = 0; j < 4; ++j) {
    int row = wrow0 + j * 16 + (lane >> 2);
    float4 v = make_float4(0.f, 0.f, 0.f, 0.f);
    if (row < nrows) v = s4[j * 64 + lane];
    float s = v.x + v.y + v.z + v.w;
    s += __shfl_xor(s, 1);
    s += __shfl_xor(s, 2);
    if ((lane & 3) == 0 && row < nrows) dst[row] = s;
  }
}

// ---------- fold: keff2[c][p][q] = 0.5*(S[p,q,c] + conj(S[-p,-q,c])), q<128 ----------
__global__ __launch_bounds__(256) void fold(
    const float* __restrict__ Sr, const float* __restrict__ Si,
    float2* __restrict__ keff2) {
  int p = blockIdx.x;
  int q = blockIdx.y * 16 + (threadIdx.x >> 4);
  int c = threadIdx.x & 15;
  int pp = (255 - p) % 255;
  int qq = (255 - q) % 255;
  size_t i0 = (size_t)(p * 255 + q) * 16 + c;
  size_t i1 = (size_t)(pp * 255 + qq) * 16 + c;
  float sr0 = Sr[i0], si0 = Si[i0], sr1 = Sr[i1], si1 = Si[i1];
  keff2[((size_t)c * 255 + p) * 128 + q] = make_float2(0.5f * (sr0 + sr1), 0.5f * (si0 - si1));
}

// ---------- twiddle operands (bf16 planes) ----------
// t2[plane6][pt16][moct16][p16][j8]: T2[p][m]=e^{-i th p m}; planes cosH,cosL,TiH,TiL,-TiH,-TiL (Ti=-sin)
// t4[plane6][ht8][poct32][h16][j8]:  T4[h][p]=e^{+i th (h+63)p}; p=255 slot zeroed (K-pad)
// t5[plane4][wt8][koct32][w16][j8]:  T5[w][k]: q=k&127; planes cosH,cosL,(-sin)H,(-sin)L
__global__ __launch_bounds__(256) void build_t24(short* __restrict__ t2,
                                                 short* __restrict__ t4,
                                                 short* __restrict__ t5) {
  int i = blockIdx.x * 256 + threadIdx.x;   // < 524288
  float s, c;
  if (i < 196608) {
    int plane = i >> 15;
    int r = i & 32767;
    int pt = r >> 11, r2 = r & 2047;
    int moct = r2 >> 7, p = (r2 >> 3) & 15, j = r2 & 7;
    int pg = pt * 16 + p, m = moct * 8 + j;
    int k = ((pg % 255) * m) % 255;
    sincosf(PI2_OVER_N * (float)k, &s, &c);
    float ti = -s;
    float src = (plane < 2) ? c : ((plane < 4) ? ti : -ti);
    unsigned short h = bf16h(src);
    t2[i] = (short)((plane & 1) ? bf16h(src - bf16f(h)) : h);
  } else if (i < 393216) {
    int i2 = i - 196608;
    int plane = i2 >> 15;
    int r = i2 & 32767;
    int ht = r >> 12, r2 = r & 4095;
    int poct = r2 >> 7, h = (r2 >> 3) & 15, j = r2 & 7;
    int p = poct * 8 + j;
    unsigned short val = 0;
    if (p < 255) {
      int hg = ht * 16 + h;
      int k = ((hg + 63) * p) % 255;
      sincosf(PI2_OVER_N * (float)k, &s, &c);
      float src = (plane < 2) ? c : ((plane < 4) ? s : -s);
      unsigned short hh = bf16h(src);
      val = (plane & 1) ? bf16h(src - bf16f(hh)) : hh;
    }
    t4[i2] = (short)val;
  } else {
    int i3 = i - 393216;
    int plane = i3 >> 15;                    // 0..3
    int r = i3 & 32767;
    int wt = r >> 12, r2 = r & 4095;
    int ko = r2 >> 7, wl = (r2 >> 3) & 15, j = r2 & 7;
    int q = (ko * 8 + j) & 127;              // k -> q (both segs identical)
    int ww = wt * 16 + wl;
    sincosf(PI2_OVER_N * (float)(((ww + 63) * q) % 255), &s, &c);
    float src = (plane < 2) ? c : -s;
    unsigned short hh = bf16h(src);
    t5[i3] = (short)((plane & 1) ? bf16h(src - bf16f(hh)) : hh);
  }
}

// ---------- stage1: U[b][c][m][q] = sum_n x[b,m,n,c] e^{-i th q n}  (VALU, fp32 out) ----------
__global__ __launch_bounds__(256) void stage1(
    const float* __restrict__ x, float4* __restrict__ U4) {
  int bm = blockIdx.x;                       // b*128 + m
  int l = threadIdx.x & 63;                  // q = 2l, 2l+1
  int g = __builtin_amdgcn_readfirstlane(threadIdx.x >> 6);
  int c = blockIdx.y * 4 + g;
  const float* xs = x + (size_t)bm * 2048 + c;
  float s0, c0, s1, c1;
  sincosf(PI2_OVER_N * (float)(2 * l), &s0, &c0);
  sincosf(PI2_OVER_N * (float)(2 * l + 1), &s1, &c1);
  float f0r = c0, f0i = -s0, f1r = c1, f1i = -s1;
  float t0r = 1.f, t0i = 0.f, t1r = 1.f, t1i = 0.f;
  float ar0 = 0.f, ai0 = 0.f, ar1 = 0.f, ai1 = 0.f;
#pragma unroll 4
  for (int n = 0; n < 128; ++n) {
    float xx = xs[n * 16];                   // wave-uniform scalar load
    ar0 += xx * t0r; ai0 += xx * t0i;
    ar1 += xx * t1r; ai1 += xx * t1i;
    cmul_update(t0r, t0i, f0r, f0i);
    cmul_update(t1r, t1i, f1r, f1i);
  }
  int b = bm >> 7, m = bm & 127;
  U4[((size_t)(b * 16 + c) * 128 + m) * 64 + l] = make_float4(ar0, ai0, ar1, ai1);
}

// ---------- pack_u: U4 fp32 -> ub bf16 splits in operand layout ----------
// ub[bc][plane4: rH,rL,iH,iL][qt8][moct16][q16][j8]
__global__ __launch_bounds__(256) void pack_u(
    const float4* __restrict__ U4, short* __restrict__ ub) {
  int bc = remap_bc(blockIdx.x);
  int mo = blockIdx.y * 2 + (threadIdx.x >> 7);
  int q = threadIdx.x & 127;
  float r[8], im[8];
#pragma unroll
  for (int j = 0; j < 8; ++j) {
    float4 u = U4[((size_t)bc * 128 + mo * 8 + j) * 64 + (q >> 1)];
    r[j]  = (q & 1) ? u.z : u.x;
    im[j] = (q & 1) ? u.w : u.y;
  }
  unsigned short hr[8], lr[8], hi_[8], li[8];
#pragma unroll
  for (int j = 0; j < 8; ++j) {
    hr[j] = bf16h(r[j]);   lr[j] = bf16h(r[j] - bf16f(hr[j]));
    hi_[j] = bf16h(im[j]); li[j] = bf16h(im[j] - bf16f(hi_[j]));
  }
  size_t base = (size_t)bc * 65536 + (size_t)(q >> 4) * 2048 + (size_t)mo * 128 + (size_t)(q & 15) * 8;
  const unsigned short* planes[4] = {hr, lr, hi_, li};
#pragma unroll
  for (int pl = 0; pl < 4; ++pl) {
    const unsigned short* v = planes[pl];
    uint4 o;
    o.x = (unsigned)v[0] | ((unsigned)v[1] << 16);
    o.y = (unsigned)v[2] | ((unsigned)v[3] << 16);
    o.z = (unsigned)v[4] | ((unsigned)v[5] << 16);
    o.w = (unsigned)v[6] | ((unsigned)v[7] << 16);
    *(uint4*)(ub + base + (size_t)pl * 16384) = o;
  }
}

// ---------- stage2_mfma: X[p][q] = sum_m T2[p][m] U[m][q]; Z = Keff*X -> zb bf16 splits ----------
// zb[bc][plane4][qt8][poct32][q16][j8] (p in k-position for stage4's A side).
__global__ __launch_bounds__(256) void stage2_mfma(
    const short* __restrict__ ub, const short* __restrict__ t2,
    const float2* __restrict__ keff2, short* __restrict__ zb) {
  int bc = remap_bc(blockIdx.x);
  int c = bc & 15;
  int w = threadIdx.x >> 6;
  int lane = threadIdx.x & 63;
  int quad = lane >> 4, col = lane & 15;
  int pt = blockIdx.y;                       // 0..15
  int qh = w;                                // 0..3 -> 2 qt each
  f32x4 accr[2] = {{0,0,0,0},{0,0,0,0}};
  f32x4 acci[2] = {{0,0,0,0},{0,0,0,0}};
  const short* ubase = ub + (size_t)bc * 65536;
#pragma unroll
  for (int ko = 0; ko < 4; ++ko) {
    int moct = ko * 4 + quad;
    const short* ta = t2 + ((size_t)(pt * 16 + moct) * 16 + col) * 8;
    bf16x8 arh = *(const bf16x8*)(ta);
    bf16x8 arl = *(const bf16x8*)(ta + 32768);
    bf16x8 aih = *(const bf16x8*)(ta + 2 * 32768);
    bf16x8 ail = *(const bf16x8*)(ta + 3 * 32768);
    bf16x8 anh = *(const bf16x8*)(ta + 4 * 32768);
    bf16x8 anl = *(const bf16x8*)(ta + 5 * 32768);
#pragma unroll
    for (int qq = 0; qq < 2; ++qq) {
      int qt = qh * 2 + qq;
      const short* tb = ubase + ((size_t)(qt * 16 + moct) * 16 + col) * 8;
      bf16x8 brh = *(const bf16x8*)(tb);
      bf16x8 brl = *(const bf16x8*)(tb + 16384);
      bf16x8 bih = *(const bf16x8*)(tb + 2 * 16384);
      bf16x8 bil = *(const bf16x8*)(tb + 3 * 16384);
      accr[qq] = MFMA16(arh, brh, accr[qq], 0, 0, 0);
      accr[qq] = MFMA16(arh, brl, accr[qq], 0, 0, 0);
      accr[qq] = MFMA16(arl, brh, accr[qq], 0, 0, 0);
      accr[qq] = MFMA16(anh, bih, accr[qq], 0, 0, 0);
      accr[qq] = MFMA16(anh, bil, accr[qq], 0, 0, 0);
      accr[qq] = MFMA16(anl, bih, accr[qq], 0, 0, 0);
      acci[qq] = MFMA16(arh, bih, acci[qq], 0, 0, 0);
      acci[qq] = MFMA16(arh, bil, acci[qq], 0, 0, 0);
      acci[qq] = MFMA16(arl, bih, acci[qq], 0, 0, 0);
      acci[qq] = MFMA16(aih, brh, acci[qq], 0, 0, 0);
      acci[qq] = MFMA16(aih, brl, acci[qq], 0, 0, 0);
      acci[qq] = MFMA16(ail, brh, acci[qq], 0, 0, 0);
    }
  }
  int poct = pt * 2 + (quad >> 1);
  size_t joff = (size_t)col * 8 + (quad & 1) * 4;
#pragma unroll
  for (int qq = 0; qq < 2; ++qq) {
    int qt = qh * 2 + qq;
    int qg = qt * 16 + col;
    float zr[4], zi[4];
#pragma unroll
    for (int r = 0; r < 4; ++r) {
      int pg = pt * 16 + quad * 4 + r;
      int pgc = pg < 255 ? pg : 254;         // keff in-bounds; p=255 slot killed by zero B in t4 k-pad
      float2 k = keff2[((size_t)c * 255 + pgc) * 128 + qg];
      float xr = accr[qq][r], xi = acci[qq][r];
      zr[r] = k.x * xr - k.y * xi;
      zi[r] = k.x * xi + k.y * xr;
    }
    unsigned short hr[4], lr[4], hi_[4], li[4];
#pragma unroll
    for (int r = 0; r < 4; ++r) {
      hr[r] = bf16h(zr[r]);  lr[r] = bf16h(zr[r] - bf16f(hr[r]));
      hi_[r] = bf16h(zi[r]); li[r] = bf16h(zi[r] - bf16f(hi_[r]));
    }
    size_t base = (size_t)bc * 131072 + (size_t)qt * 4096 + (size_t)poct * 128 + joff;
    uint2 o;
    o.x = (unsigned)hr[0] | ((unsigned)hr[1] << 16);
    o.y = (unsigned)hr[2] | ((unsigned)hr[3] << 16);
    *(uint2*)(zb + base) = o;
    o.x = (unsigned)lr[0] | ((unsigned)lr[1] << 16);
    o.y = (unsigned)lr[2] | ((unsigned)lr[3] << 16);
    *(uint2*)(zb + base + 32768) = o;
    o.x = (unsigned)hi_[0] | ((unsigned)hi_[1] << 16);
    o.y = (unsigned)hi_[2] | ((unsigned)hi_[3] << 16);
    *(uint2*)(zb + base + 2 * 32768) = o;
    o.x = (unsigned)li[0] | ((unsigned)li[1] << 16);
    o.y = (unsigned)li[2] | ((unsigned)li[3] << 16);
    *(uint2*)(zb + base + 3 * 32768) = o;
  }
}

// ---------- stage4_mfma (operands SWAPPED: A=Z -> D rows=q, B=T4 -> D cols=h) ----------
// Epilogue writes V bf16 hi/lo splits directly into stage5's A-operand layout:
// a5[bc][plane4: VrH,VrL,ViH,ViL][ht8][koct32][h16][j8], k = kseg*128 + q.
// Also v0[kseg*64+bc][h] = Vr_seg[h][q=0] (fp32) for stage5's half-term fix.
__global__ __launch_bounds__(256) void stage4_mfma(
    const short* __restrict__ zb, const short* __restrict__ t4,
    short* __restrict__ a5, float* __restrict__ v0) {
  int bc = remap_bc(blockIdx.x);
  int w = threadIdx.x >> 6;
  int lane = threadIdx.x & 63;
  int quad = lane >> 4, col = lane & 15;
  int u = blockIdx.y * 4 + w;                // 0..63
  int qt = u >> 3;                           // 0..7 (q-tile -> D rows)
  int kseg = (u >> 2) & 1;                   // p-segment
  int htp = u & 3;                           // 2 h-tiles: htp*2, htp*2+1
  f32x4 accr[2] = {{0,0,0,0},{0,0,0,0}};
  f32x4 acci[2] = {{0,0,0,0},{0,0,0,0}};
  const short* zbase = zb + (size_t)bc * 131072;
#pragma unroll
  for (int ko = 0; ko < 4; ++ko) {
    int poct = kseg * 16 + ko * 4 + quad;
    const short* tz = zbase + ((size_t)(qt * 32 + poct) * 16 + col) * 8;
    bf16x8 zrh = *(const bf16x8*)(tz);
    bf16x8 zrl = *(const bf16x8*)(tz + 32768);
    bf16x8 zih = *(const bf16x8*)(tz + 2 * 32768);
    bf16x8 zil = *(const bf16x8*)(tz + 3 * 32768);
#pragma unroll
    for (int t = 0; t < 2; ++t) {
      int ht = htp * 2 + t;
      const short* ta = t4 + ((size_t)(ht * 32 + poct) * 16 + col) * 8;
      bf16x8 trh = *(const bf16x8*)(ta);
      bf16x8 trl = *(const bf16x8*)(ta + 32768);
      bf16x8 tih = *(const bf16x8*)(ta + 2 * 32768);
      bf16x8 til = *(const bf16x8*)(ta + 3 * 32768);
      bf16x8 tnh = *(const bf16x8*)(ta + 4 * 32768);
      bf16x8 tnl = *(const bf16x8*)(ta + 5 * 32768);
      // Vr = Zr*Tr + Zi*(-Ti)
      accr[t] = MFMA16(zrh, trh, accr[t], 0, 0, 0);
      accr[t] = MFMA16(zrh, trl, accr[t], 0, 0, 0);
      accr[t] = MFMA16(zrl, trh, accr[t], 0, 0, 0);
      accr[t] = MFMA16(zih, tnh, accr[t], 0, 0, 0);
      accr[t] = MFMA16(zih, tnl, accr[t], 0, 0, 0);
      accr[t] = MFMA16(zil, tnh, accr[t], 0, 0, 0);
      // Vi = Zi*Tr + Zr*Ti
      acci[t] = MFMA16(zih, trh, acci[t], 0, 0, 0);
      acci[t] = MFMA16(zih, trl, acci[t], 0, 0, 0);
      acci[t] = MFMA16(zil, trh, acci[t], 0, 0, 0);
      acci[t] = MFMA16(zrh, tih, acci[t], 0, 0, 0);
      acci[t] = MFMA16(zrh, til, acci[t], 0, 0, 0);
      acci[t] = MFMA16(zrl, tih, acci[t], 0, 0, 0);
    }
  }
  // lane rows: q = qt*16 + quad*4 + r  ->  k = kseg*128 + q (contiguous in r)
  int ko_s = kseg * 16 + qt * 2 + (quad >> 1);
  int j0 = (quad & 1) * 4;
#pragma unroll
  for (int t = 0; t < 2; ++t) {
    int ht = htp * 2 + t;
    unsigned short vh[4], vl[4], wh[4], wl2[4];
#pragma unroll
    for (int r = 0; r < 4; ++r) {
      vh[r] = bf16h(accr[t][r]);  vl[r] = bf16h(accr[t][r] - bf16f(vh[r]));
      wh[r] = bf16h(acci[t][r]);  wl2[r] = bf16h(acci[t][r] - bf16f(wh[r]));
    }
    size_t base = (((size_t)(bc * 4) * 8 + ht) * 32 + ko_s) * 128 + (size_t)col * 8 + j0;
    uint2 o;
    o.x = (unsigned)vh[0] | ((unsigned)vh[1] << 16);
    o.y = (unsigned)vh[2] | ((unsigned)vh[3] << 16);
    *(uint2*)(a5 + base) = o;
    o.x = (unsigned)vl[0] | ((unsigned)vl[1] << 16);
    o.y = (unsigned)vl[2] | ((unsigned)vl[3] << 16);
    *(uint2*)(a5 + base + 32768) = o;
    o.x = (unsigned)wh[0] | ((unsigned)wh[1] << 16);
    o.y = (unsigned)wh[2] | ((unsigned)wh[3] << 16);
    *(uint2*)(a5 + base + 2 * 32768) = o;
    o.x = (unsigned)wl2[0] | ((unsigned)wl2[1] << 16);
    o.y = (unsigned)wl2[2] | ((unsigned)wl2[3] << 16);
    *(uint2*)(a5 + base + 3 * 32768) = o;
    if (qt == 0 && quad == 0)                // row 0 => q = 0
      v0[(size_t)(kseg * 64 + bc) * 128 + ht * 16 + col] = accr[t][0];
  }
}

// ---------- stage5_mfma: O[h][w] = sum_{k=0..255} (Vr*cos + Vi*(-sin)) ; out = (2O - v0)*1/N^2 + bias ----------
// A = a5 (h -> D rows), B = t5 (w -> D cols). K=256 folds both p-segments (sum free in acc).
__global__ __launch_bounds__(256) void stage5_mfma(
    const short* __restrict__ a5, const short* __restrict__ t5,
    const float* __restrict__ v0, const float* __restrict__ bias,
    float* __restrict__ out) {
  int bc = remap_bc(blockIdx.x);
  int w = threadIdx.x >> 6;
  int lane = threadIdx.x & 63;
  int quad = lane >> 4, col = lane & 15;
  int u = blockIdx.y * 4 + w;                // 0..31
  int ht = u >> 2;                           // 0..7
  int wtp = u & 3;                           // 2 w-tiles
  f32x4 acc[2] = {{0,0,0,0},{0,0,0,0}};
  const short* abase = a5 + (size_t)bc * 131072;
#pragma unroll
  for (int kc = 0; kc < 8; ++kc) {
    int koq = kc * 4 + quad;                 // k-oct 0..31
    const short* pa = abase + ((size_t)(ht * 32 + koq) * 16 + col) * 8;
    bf16x8 vrh = *(const bf16x8*)(pa);
    bf16x8 vrl = *(const bf16x8*)(pa + 32768);
    bf16x8 vih = *(const bf16x8*)(pa + 2 * 32768);
    bf16x8 vil = *(const bf16x8*)(pa + 3 * 32768);
#pragma unroll
    for (int t = 0; t < 2; ++t) {
      int wt = wtp * 2 + t;
      const short* pb = t5 + ((size_t)(wt * 32 + koq) * 16 + col) * 8;
      bf16x8 tch = *(const bf16x8*)(pb);
      bf16x8 tcl = *(const bf16x8*)(pb + 32768);
      bf16x8 tnh = *(const bf16x8*)(pb + 2 * 32768);
      bf16x8 tnl = *(const bf16x8*)(pb + 3 * 32768);
      acc[t] = MFMA16(vrh, tch, acc[t], 0, 0, 0);
      acc[t] = MFMA16(vrh, tcl, acc[t], 0, 0, 0);
      acc[t] = MFMA16(vrl, tch, acc[t], 0, 0, 0);
      acc[t] = MFMA16(vih, tnh, acc[t], 0, 0, 0);
      acc[t] = MFMA16(vih, tnl, acc[t], 0, 0, 0);
      acc[t] = MFMA16(vil, tnh, acc[t], 0, 0, 0);
    }
  }
  int b = bc >> 4, c = bc & 15;
  float bb = bias[c];
  float v0t[4];
#pragma unroll
  for (int r = 0; r < 4; ++r) {
    int h = ht * 16 + quad * 4 + r;
    v0t[r] = v0[(size_t)bc * 128 + h] + v0[(size_t)(64 + bc) * 128 + h];
  }
#pragma unroll
  for (int t = 0; t < 2; ++t) {
    int ww = (wtp * 2 + t) * 16 + col;
#pragma unroll
    for (int r = 0; r < 4; ++r) {
      int h = ht * 16 + quad * 4 + r;
      out[((size_t)(b * 128 + h) * 128 + ww) * 16 + c] =
          (2.0f * acc[t][r] - v0t[r]) * INV_N2 + bb;
    }
  }
}

extern "C" void kernel_launch(void* const* d_in, const int* in_sizes, int n_in,
                              void* d_out, int out_size, void* d_ws, size_t ws_size,
                              hipStream_t stream) {
  const float* x  = (const float*)d_in[0];
  const float* kr = (const float*)d_in[1];
  const float* ki = (const float*)d_in[2];
  const float* bs = (const float*)d_in[3];
  float* out = (float*)d_out;

  char* p = (char*)d_ws;
  float2* keff2 = (float2*)p; p += (size_t)16 * 255 * 128 * 8;    // 4.18 MB
  short*  zb    = (short*)p;  p += (size_t)64 * 131072 * 2;       // 16.78 MB
  float4* U4    = (float4*)p;                                      // 8.39 MB
  short*  a5    = (short*)p;  p += (size_t)64 * 131072 * 2;       // 16.78 MB (overlays U4+ub)
  short*  ub    = (short*)p;  p += (size_t)64 * 65536 * 2;        // (second half of a5 region)
  short*  t2    = (short*)p;  p += (size_t)196608 * 2;            // 0.39 MB
  short*  t4    = (short*)p;  p += (size_t)196608 * 2;            // 0.39 MB
  short*  t5    = (short*)p;  p += (size_t)131072 * 2;            // 0.26 MB
  float*  v0    = (float*)p;  p += (size_t)2 * 64 * 128 * 4;      // 64 KB
  // Sr/Si (8.33 MB) overlay zb (dead after fold; zb written later by stage2).
  float* Sr = (float*)zb;
  float* Si = Sr + 255 * 255 * 16;
  // ub sits in the upper half of the a5 region: U4 dead after pack_u, ub dead after
  // stage2; stage4 then overwrites the whole region with a5.

  ksum<<<dim3(4065, 2), 256, 0, stream>>>(kr, ki, Sr, Si);
  fold<<<dim3(255, 8), 256, 0, stream>>>(Sr, Si, keff2);
  build_t24<<<2048, 256, 0, stream>>>(t2, t4, t5);
  stage1<<<dim3(512, 4), 256, 0, stream>>>(x, U4);
  pack_u<<<dim3(64, 8), 256, 0, stream>>>(U4, ub);
  stage2_mfma<<<dim3(64, 16), 256, 0, stream>>>(ub, t2, keff2, zb);
  stage4_mfma<<<dim3(64, 16), 256, 0, stream>>>(zb, t4, a5, v0);
  stage5_mfma<<<dim3(64, 8), 256, 0, stream>>>(a5, t5, v0, bs, out);
}

// Round 2
// 218.690 us; speedup vs baseline: 1.1307x; 1.1307x over previous
//
#include <hip/hip_runtime.h>
#include <math.h>

// FourierConv via DFT-as-GEMM on the MATRIX pipe.
// out[b,h,w,c] = Re(ifft2(fft2(x,255^2)*Ksum))[h+63,w+63] + bias; Ksum = sum_cout K.
// Half-spectrum q=0..127. Stages 2 (m->p), 4 (p->h), 5 (q->w real part) are bf16 MFMA
// GEMMs with SPLIT precision: a*b ~= aH*bH + aH*bL + aL*bH (rel err ~2^-17).
// Operand-fragment rule (verified): both MFMA operands use layout [entity=lane&15][k=quad*8+j];
// first arg's entity -> D row (quad*4+reg), second arg's entity -> D col (lane&15).
// stage4 computes D[q][h] (A=Z, B=T4) so its epilogue emits V directly in stage5's
// A-operand bf16 layout (a5) -- k-contiguous per lane. stage5 is a K=256 GEMM (2 p-segs
// folded into K; seg-sum is free in the accumulator) + (2S - v0)*1/N^2 + bias epilogue.
//
// R1: ksum/stage1/build_t24 are mutually independent; fused into ONE kernel with
// block-striping (2 ksum : 1 compute) so the HBM stream (ksum, ~2.7 TB/s delivered cap,
// VALU idle) overlaps the sincos VALU work (stage1/build) on the same CUs. ksum body
// reverted to the R0 per-thread-row form (R1 coalesced variant was -5us: the limiter is
// per-CU read-miss throughput, not address pattern -- both patterns hit ~2.7 TB/s).

constexpr float PI2_OVER_N = 6.28318530717958647692f / 255.0f;
constexpr float INV_N2 = 1.0f / (255.0f * 255.0f);

typedef __attribute__((ext_vector_type(8))) short bf16x8;   // 8 bf16 = 4 VGPR
typedef __attribute__((ext_vector_type(4))) float f32x4;    // MFMA acc
#define MFMA16 __builtin_amdgcn_mfma_f32_16x16x32_bf16

__device__ __forceinline__ int remap_bc(int xidx) {
  int k = xidx & 7, j = xidx >> 3;
  return ((k >> 1) * 16) + ((k & 1) * 8) + j;   // b = k>>1, c = (k&1)*8 + j
}

__device__ __forceinline__ void cmul_update(float& tr, float& ti, float fr, float fi) {
  float ntr = tr * fr - ti * fi;
  ti = tr * fi + ti * fr;
  tr = ntr;
}

__device__ __forceinline__ unsigned short bf16h(float f) {
  unsigned u = __float_as_uint(f);
  return (unsigned short)((u + 0x7FFFu + ((u >> 16) & 1u)) >> 16);
}
__device__ __forceinline__ float bf16f(unsigned short h) {
  return __uint_as_float(((unsigned)h) << 16);
}

// ---------- fused front: ksum + stage1 + build_t24 (independent work, co-scheduled) ----------
// Block stripe of 3: r3 in {0,1} -> ksum block (8192 total, 4065x2 used);
// r3 == 2 -> compute block: cid<2048 = stage1, else build_t24.

__device__ __forceinline__ void ksum_body(
    int buf, int xb, const float* __restrict__ kr, const float* __restrict__ ki,
    float* __restrict__ Sr, float* __restrict__ Si) {
  const int nrows = 255 * 255 * 16;
  int r = xb * 256 + threadIdx.x;
  if (r >= nrows) return;
  const float* src = (buf == 0) ? kr : ki;
  float* dst = (buf == 0) ? Sr : Si;
  const float4* k4 = (const float4*)(src + (size_t)r * 16);
  float4 a = k4[0], b = k4[1], c = k4[2], d = k4[3];
  dst[r] = a.x + a.y + a.z + a.w + b.x + b.y + b.z + b.w +
           c.x + c.y + c.z + c.w + d.x + d.y + d.z + d.w;
}

__device__ __forceinline__ void stage1_body(
    int cid, const float* __restrict__ x, float4* __restrict__ U4) {
  int bm = cid & 511;                        // b*128 + m
  int yc = cid >> 9;                         // 0..3
  int l = threadIdx.x & 63;                  // q = 2l, 2l+1
  int g = __builtin_amdgcn_readfirstlane(threadIdx.x >> 6);
  int c = yc * 4 + g;
  const float* xs = x + (size_t)bm * 2048 + c;
  float s0, c0, s1, c1;
  sincosf(PI2_OVER_N * (float)(2 * l), &s0, &c0);
  sincosf(PI2_OVER_N * (float)(2 * l + 1), &s1, &c1);
  float f0r = c0, f0i = -s0, f1r = c1, f1i = -s1;
  float t0r = 1.f, t0i = 0.f, t1r = 1.f, t1i = 0.f;
  float ar0 = 0.f, ai0 = 0.f, ar1 = 0.f, ai1 = 0.f;
#pragma unroll 4
  for (int n = 0; n < 128; ++n) {
    float xx = xs[n * 16];                   // wave-uniform scalar load
    ar0 += xx * t0r; ai0 += xx * t0i;
    ar1 += xx * t1r; ai1 += xx * t1i;
    cmul_update(t0r, t0i, f0r, f0i);
    cmul_update(t1r, t1i, f1r, f1i);
  }
  int b = bm >> 7, m = bm & 127;
  U4[((size_t)(b * 16 + c) * 128 + m) * 64 + l] = make_float4(ar0, ai0, ar1, ai1);
}

__device__ __forceinline__ void build_body(
    int cid2, short* __restrict__ t2, short* __restrict__ t4, short* __restrict__ t5) {
  int i = cid2 * 256 + threadIdx.x;          // < 524288
  float s, c;
  if (i < 196608) {
    int plane = i >> 15;
    int r = i & 32767;
    int pt = r >> 11, r2 = r & 2047;
    int moct = r2 >> 7, p = (r2 >> 3) & 15, j = r2 & 7;
    int pg = pt * 16 + p, m = moct * 8 + j;
    int k = ((pg % 255) * m) % 255;
    sincosf(PI2_OVER_N * (float)k, &s, &c);
    float ti = -s;
    float src = (plane < 2) ? c : ((plane < 4) ? ti : -ti);
    unsigned short h = bf16h(src);
    t2[i] = (short)((plane & 1) ? bf16h(src - bf16f(h)) : h);
  } else if (i < 393216) {
    int i2 = i - 196608;
    int plane = i2 >> 15;
    int r = i2 & 32767;
    int ht = r >> 12, r2 = r & 4095;
    int poct = r2 >> 7, h = (r2 >> 3) & 15, j = r2 & 7;
    int p = poct * 8 + j;
    unsigned short val = 0;
    if (p < 255) {
      int hg = ht * 16 + h;
      int k = ((hg + 63) * p) % 255;
      sincosf(PI2_OVER_N * (float)k, &s, &c);
      float src = (plane < 2) ? c : ((plane < 4) ? s : -s);
      unsigned short hh = bf16h(src);
      val = (plane & 1) ? bf16h(src - bf16f(hh)) : hh;
    }
    t4[i2] = (short)val;
  } else {
    int i3 = i - 393216;
    int plane = i3 >> 15;                    // 0..3
    int r = i3 & 32767;
    int wt = r >> 12, r2 = r & 4095;
    int ko = r2 >> 7, wl = (r2 >> 3) & 15, j = r2 & 7;
    int q = (ko * 8 + j) & 127;              // k -> q (both segs identical)
    int ww = wt * 16 + wl;
    sincosf(PI2_OVER_N * (float)(((ww + 63) * q) % 255), &s, &c);
    float src = (plane < 2) ? c : -s;
    unsigned short hh = bf16h(src);
    t5[i3] = (short)((plane & 1) ? bf16h(src - bf16f(hh)) : hh);
  }
}

__global__ __launch_bounds__(256) void fused_front(
    const float* __restrict__ kr, const float* __restrict__ ki,
    float* __restrict__ Sr, float* __restrict__ Si,
    const float* __restrict__ x, float4* __restrict__ U4,
    short* __restrict__ t2, short* __restrict__ t4, short* __restrict__ t5) {
  int bid = blockIdx.x;                      // 0..12287
  int d3 = bid / 3, r3 = bid - d3 * 3;
  if (r3 == 2) {
    int cid = d3;                            // 0..4095
    if (cid < 2048) stage1_body(cid, x, U4);
    else            build_body(cid - 2048, t2, t4, t5);
  } else {
    int kid = d3 * 2 + r3;                   // 0..8191
    ksum_body(kid & 1, kid >> 1, kr, ki, Sr, Si);
  }
}

// ---------- fold: keff2[c][p][q] = 0.5*(S[p,q,c] + conj(S[-p,-q,c])), q<128 ----------
__global__ __launch_bounds__(256) void fold(
    const float* __restrict__ Sr, const float* __restrict__ Si,
    float2* __restrict__ keff2) {
  int p = blockIdx.x;
  int q = blockIdx.y * 16 + (threadIdx.x >> 4);
  int c = threadIdx.x & 15;
  int pp = (255 - p) % 255;
  int qq = (255 - q) % 255;
  size_t i0 = (size_t)(p * 255 + q) * 16 + c;
  size_t i1 = (size_t)(pp * 255 + qq) * 16 + c;
  float sr0 = Sr[i0], si0 = Si[i0], sr1 = Sr[i1], si1 = Si[i1];
  float2 v;
  v.x = 0.5f * (sr0 + sr1);
  v.y = 0.5f * (si0 - si1);
  keff2[((size_t)c * 255 + p) * 128 + q] = v;
}

// ---------- pack_u: U4 fp32 -> ub bf16 splits in operand layout ----------
// ub[bc][plane4: rH,rL,iH,iL][qt8][moct16][q16][j8]
__global__ __launch_bounds__(256) void pack_u(
    const float4* __restrict__ U4, short* __restrict__ ub) {
  int bc = remap_bc(blockIdx.x);
  int mo = blockIdx.y * 2 + (threadIdx.x >> 7);
  int q = threadIdx.x & 127;
  float r[8], im[8];
#pragma unroll
  for (int j = 0; j < 8; ++j) {
    float4 u = U4[((size_t)bc * 128 + mo * 8 + j) * 64 + (q >> 1)];
    r[j]  = (q & 1) ? u.z : u.x;
    im[j] = (q & 1) ? u.w : u.y;
  }
  unsigned short hr[8], lr[8], hi_[8], li[8];
#pragma unroll
  for (int j = 0; j < 8; ++j) {
    hr[j] = bf16h(r[j]);   lr[j] = bf16h(r[j] - bf16f(hr[j]));
    hi_[j] = bf16h(im[j]); li[j] = bf16h(im[j] - bf16f(hi_[j]));
  }
  size_t base = (size_t)bc * 65536 + (size_t)(q >> 4) * 2048 + (size_t)mo * 128 + (size_t)(q & 15) * 8;
  const unsigned short* planes[4] = {hr, lr, hi_, li};
#pragma unroll
  for (int pl = 0; pl < 4; ++pl) {
    const unsigned short* v = planes[pl];
    uint4 o;
    o.x = (unsigned)v[0] | ((unsigned)v[1] << 16);
    o.y = (unsigned)v[2] | ((unsigned)v[3] << 16);
    o.z = (unsigned)v[4] | ((unsigned)v[5] << 16);
    o.w = (unsigned)v[6] | ((unsigned)v[7] << 16);
    *(uint4*)(ub + base + (size_t)pl * 16384) = o;
  }
}

// ---------- stage2_mfma: X[p][q] = sum_m T2[p][m] U[m][q]; Z = Keff*X -> zb bf16 splits ----------
// zb[bc][plane4][qt8][poct32][q16][j8] (p in k-position for stage4's A side).
__global__ __launch_bounds__(256) void stage2_mfma(
    const short* __restrict__ ub, const short* __restrict__ t2,
    const float2* __restrict__ keff2, short* __restrict__ zb) {
  int bc = remap_bc(blockIdx.x);
  int c = bc & 15;
  int w = threadIdx.x >> 6;
  int lane = threadIdx.x & 63;
  int quad = lane >> 4, col = lane & 15;
  int pt = blockIdx.y;                       // 0..15
  int qh = w;                                // 0..3 -> 2 qt each
  f32x4 accr[2] = {{0,0,0,0},{0,0,0,0}};
  f32x4 acci[2] = {{0,0,0,0},{0,0,0,0}};
  const short* ubase = ub + (size_t)bc * 65536;
#pragma unroll
  for (int ko = 0; ko < 4; ++ko) {
    int moct = ko * 4 + quad;
    const short* ta = t2 + ((size_t)(pt * 16 + moct) * 16 + col) * 8;
    bf16x8 arh = *(const bf16x8*)(ta);
    bf16x8 arl = *(const bf16x8*)(ta + 32768);
    bf16x8 aih = *(const bf16x8*)(ta + 2 * 32768);
    bf16x8 ail = *(const bf16x8*)(ta + 3 * 32768);
    bf16x8 anh = *(const bf16x8*)(ta + 4 * 32768);
    bf16x8 anl = *(const bf16x8*)(ta + 5 * 32768);
#pragma unroll
    for (int qq = 0; qq < 2; ++qq) {
      int qt = qh * 2 + qq;
      const short* tb = ubase + ((size_t)(qt * 16 + moct) * 16 + col) * 8;
      bf16x8 brh = *(const bf16x8*)(tb);
      bf16x8 brl = *(const bf16x8*)(tb + 16384);
      bf16x8 bih = *(const bf16x8*)(tb + 2 * 16384);
      bf16x8 bil = *(const bf16x8*)(tb + 3 * 16384);
      accr[qq] = MFMA16(arh, brh, accr[qq], 0, 0, 0);
      accr[qq] = MFMA16(arh, brl, accr[qq], 0, 0, 0);
      accr[qq] = MFMA16(arl, brh, accr[qq], 0, 0, 0);
      accr[qq] = MFMA16(anh, bih, accr[qq], 0, 0, 0);
      accr[qq] = MFMA16(anh, bil, accr[qq], 0, 0, 0);
      accr[qq] = MFMA16(anl, bih, accr[qq], 0, 0, 0);
      acci[qq] = MFMA16(arh, bih, acci[qq], 0, 0, 0);
      acci[qq] = MFMA16(arh, bil, acci[qq], 0, 0, 0);
      acci[qq] = MFMA16(arl, bih, acci[qq], 0, 0, 0);
      acci[qq] = MFMA16(aih, brh, acci[qq], 0, 0, 0);
      acci[qq] = MFMA16(aih, brl, acci[qq], 0, 0, 0);
      acci[qq] = MFMA16(ail, brh, acci[qq], 0, 0, 0);
    }
  }
  int poct = pt * 2 + (quad >> 1);
  size_t joff = (size_t)col * 8 + (quad & 1) * 4;
#pragma unroll
  for (int qq = 0; qq < 2; ++qq) {
    int qt = qh * 2 + qq;
    int qg = qt * 16 + col;
    float zr[4], zi[4];
#pragma unroll
    for (int r = 0; r < 4; ++r) {
      int pg = pt * 16 + quad * 4 + r;
      int pgc = pg < 255 ? pg : 254;         // keff in-bounds; p=255 slot killed by zero B in t4 k-pad
      float2 k = keff2[((size_t)c * 255 + pgc) * 128 + qg];
      float xr = accr[qq][r], xi = acci[qq][r];
      zr[r] = k.x * xr - k.y * xi;
      zi[r] = k.x * xi + k.y * xr;
    }
    unsigned short hr[4], lr[4], hi_[4], li[4];
#pragma unroll
    for (int r = 0; r < 4; ++r) {
      hr[r] = bf16h(zr[r]);  lr[r] = bf16h(zr[r] - bf16f(hr[r]));
      hi_[r] = bf16h(zi[r]); li[r] = bf16h(zi[r] - bf16f(hi_[r]));
    }
    size_t base = (size_t)bc * 131072 + (size_t)qt * 4096 + (size_t)poct * 128 + joff;
    uint2 o;
    o.x = (unsigned)hr[0] | ((unsigned)hr[1] << 16);
    o.y = (unsigned)hr[2] | ((unsigned)hr[3] << 16);
    *(uint2*)(zb + base) = o;
    o.x = (unsigned)lr[0] | ((unsigned)lr[1] << 16);
    o.y = (unsigned)lr[2] | ((unsigned)lr[3] << 16);
    *(uint2*)(zb + base + 32768) = o;
    o.x = (unsigned)hi_[0] | ((unsigned)hi_[1] << 16);
    o.y = (unsigned)hi_[2] | ((unsigned)hi_[3] << 16);
    *(uint2*)(zb + base + 2 * 32768) = o;
    o.x = (unsigned)li[0] | ((unsigned)li[1] << 16);
    o.y = (unsigned)li[2] | ((unsigned)li[3] << 16);
    *(uint2*)(zb + base + 3 * 32768) = o;
  }
}

// ---------- stage4_mfma (operands SWAPPED: A=Z -> D rows=q, B=T4 -> D cols=h) ----------
// Epilogue writes V bf16 hi/lo splits directly into stage5's A-operand layout:
// a5[bc][plane4: VrH,VrL,ViH,ViL][ht8][koct32][h16][j8], k = kseg*128 + q.
// Also v0[kseg*64+bc][h] = Vr_seg[h][q=0] (fp32) for stage5's half-term fix.
__global__ __launch_bounds__(256) void stage4_mfma(
    const short* __restrict__ zb, const short* __restrict__ t4,
    short* __restrict__ a5, float* __restrict__ v0) {
  int bc = remap_bc(blockIdx.x);
  int w = threadIdx.x >> 6;
  int lane = threadIdx.x & 63;
  int quad = lane >> 4, col = lane & 15;
  int u = blockIdx.y * 4 + w;                // 0..63
  int qt = u >> 3;                           // 0..7 (q-tile -> D rows)
  int kseg = (u >> 2) & 1;                   // p-segment
  int htp = u & 3;                           // 2 h-tiles: htp*2, htp*2+1
  f32x4 accr[2] = {{0,0,0,0},{0,0,0,0}};
  f32x4 acci[2] = {{0,0,0,0},{0,0,0,0}};
  const short* zbase = zb + (size_t)bc * 131072;
#pragma unroll
  for (int ko = 0; ko < 4; ++ko) {
    int poct = kseg * 16 + ko * 4 + quad;
    const short* tz = zbase + ((size_t)(qt * 32 + poct) * 16 + col) * 8;
    bf16x8 zrh = *(const bf16x8*)(tz);
    bf16x8 zrl = *(const bf16x8*)(tz + 32768);
    bf16x8 zih = *(const bf16x8*)(tz + 2 * 32768);
    bf16x8 zil = *(const bf16x8*)(tz + 3 * 32768);
#pragma unroll
    for (int t = 0; t < 2; ++t) {
      int ht = htp * 2 + t;
      const short* ta = t4 + ((size_t)(ht * 32 + poct) * 16 + col) * 8;
      bf16x8 trh = *(const bf16x8*)(ta);
      bf16x8 trl = *(const bf16x8*)(ta + 32768);
      bf16x8 tih = *(const bf16x8*)(ta + 2 * 32768);
      bf16x8 til = *(const bf16x8*)(ta + 3 * 32768);
      bf16x8 tnh = *(const bf16x8*)(ta + 4 * 32768);
      bf16x8 tnl = *(const bf16x8*)(ta + 5 * 32768);
      // Vr = Zr*Tr + Zi*(-Ti)
      accr[t] = MFMA16(zrh, trh, accr[t], 0, 0, 0);
      accr[t] = MFMA16(zrh, trl, accr[t], 0, 0, 0);
      accr[t] = MFMA16(zrl, trh, accr[t], 0, 0, 0);
      accr[t] = MFMA16(zih, tnh, accr[t], 0, 0, 0);
      accr[t] = MFMA16(zih, tnl, accr[t], 0, 0, 0);
      accr[t] = MFMA16(zil, tnh, accr[t], 0, 0, 0);
      // Vi = Zi*Tr + Zr*Ti
      acci[t] = MFMA16(zih, trh, acci[t], 0, 0, 0);
      acci[t] = MFMA16(zih, trl, acci[t], 0, 0, 0);
      acci[t] = MFMA16(zil, trh, acci[t], 0, 0, 0);
      acci[t] = MFMA16(zrh, tih, acci[t], 0, 0, 0);
      acci[t] = MFMA16(zrh, til, acci[t], 0, 0, 0);
      acci[t] = MFMA16(zrl, tih, acci[t], 0, 0, 0);
    }
  }
  // lane rows: q = qt*16 + quad*4 + r  ->  k = kseg*128 + q (contiguous in r)
  int ko_s = kseg * 16 + qt * 2 + (quad >> 1);
  int j0 = (quad & 1) * 4;
#pragma unroll
  for (int t = 0; t < 2; ++t) {
    int ht = htp * 2 + t;
    unsigned short vh[4], vl[4], wh[4], wl2[4];
#pragma unroll
    for (int r = 0; r < 4; ++r) {
      vh[r] = bf16h(accr[t][r]);  vl[r] = bf16h(accr[t][r] - bf16f(vh[r]));
      wh[r] = bf16h(acci[t][r]);  wl2[r] = bf16h(acci[t][r] - bf16f(wh[r]));
    }
    size_t base = (((size_t)(bc * 4) * 8 + ht) * 32 + ko_s) * 128 + (size_t)col * 8 + j0;
    uint2 o;
    o.x = (unsigned)vh[0] | ((unsigned)vh[1] << 16);
    o.y = (unsigned)vh[2] | ((unsigned)vh[3] << 16);
    *(uint2*)(a5 + base) = o;
    o.x = (unsigned)vl[0] | ((unsigned)vl[1] << 16);
    o.y = (unsigned)vl[2] | ((unsigned)vl[3] << 16);
    *(uint2*)(a5 + base + 32768) = o;
    o.x = (unsigned)wh[0] | ((unsigned)wh[1] << 16);
    o.y = (unsigned)wh[2] | ((unsigned)wh[3] << 16);
    *(uint2*)(a5 + base + 2 * 32768) = o;
    o.x = (unsigned)wl2[0] | ((unsigned)wl2[1] << 16);
    o.y = (unsigned)wl2[2] | ((unsigned)wl2[3] << 16);
    *(uint2*)(a5 + base + 3 * 32768) = o;
    if (qt == 0 && quad == 0)                // row 0 => q = 0
      v0[(size_t)(kseg * 64 + bc) * 128 + ht * 16 + col] = accr[t][0];
  }
}

// ---------- stage5_mfma: O[h][w] = sum_{k=0..255} (Vr*cos + Vi*(-sin)) ; out = (2O - v0)*1/N^2 + bias ----------
// A = a5 (h -> D rows), B = t5 (w -> D cols). K=256 folds both p-segments (sum free in acc).
__global__ __launch_bounds__(256) void stage5_mfma(
    const short* __restrict__ a5, const short* __restrict__ t5,
    const float* __restrict__ v0, const float* __restrict__ bias,
    float* __restrict__ out) {
  int bc = remap_bc(blockIdx.x);
  int w = threadIdx.x >> 6;
  int lane = threadIdx.x & 63;
  int quad = lane >> 4, col = lane & 15;
  int u = blockIdx.y * 4 + w;                // 0..31
  int ht = u >> 2;                           // 0..7
  int wtp = u & 3;                           // 2 w-tiles
  f32x4 acc[2] = {{0,0,0,0},{0,0,0,0}};
  const short* abase = a5 + (size_t)bc * 131072;
#pragma unroll
  for (int kc = 0; kc < 8; ++kc) {
    int koq = kc * 4 + quad;                 // k-oct 0..31
    const short* pa = abase + ((size_t)(ht * 32 + koq) * 16 + col) * 8;
    bf16x8 vrh = *(const bf16x8*)(pa);
    bf16x8 vrl = *(const bf16x8*)(pa + 32768);
    bf16x8 vih = *(const bf16x8*)(pa + 2 * 32768);
    bf16x8 vil = *(const bf16x8*)(pa + 3 * 32768);
#pragma unroll
    for (int t = 0; t < 2; ++t) {
      int wt = wtp * 2 + t;
      const short* pb = t5 + ((size_t)(wt * 32 + koq) * 16 + col) * 8;
      bf16x8 tch = *(const bf16x8*)(pb);
      bf16x8 tcl = *(const bf16x8*)(pb + 32768);
      bf16x8 tnh = *(const bf16x8*)(pb + 2 * 32768);
      bf16x8 tnl = *(const bf16x8*)(pb + 3 * 32768);
      acc[t] = MFMA16(vrh, tch, acc[t], 0, 0, 0);
      acc[t] = MFMA16(vrh, tcl, acc[t], 0, 0, 0);
      acc[t] = MFMA16(vrl, tch, acc[t], 0, 0, 0);
      acc[t] = MFMA16(vih, tnh, acc[t], 0, 0, 0);
      acc[t] = MFMA16(vih, tnl, acc[t], 0, 0, 0);
      acc[t] = MFMA16(vil, tnh, acc[t], 0, 0, 0);
    }
  }
  int b = bc >> 4, c = bc & 15;
  float bb = bias[c];
  float v0t[4];
#pragma unroll
  for (int r = 0; r < 4; ++r) {
    int h = ht * 16 + quad * 4 + r;
    v0t[r] = v0[(size_t)bc * 128 + h] + v0[(size_t)(64 + bc) * 128 + h];
  }
#pragma unroll
  for (int t = 0; t < 2; ++t) {
    int ww = (wtp * 2 + t) * 16 + col;
#pragma unroll
    for (int r = 0; r < 4; ++r) {
      int h = ht * 16 + quad * 4 + r;
      out[((size_t)(b * 128 + h) * 128 + ww) * 16 + c] =
          (2.0f * acc[t][r] - v0t[r]) * INV_N2 + bb;
    }
  }
}

extern "C" void kernel_launch(void* const* d_in, const int* in_sizes, int n_in,
                              void* d_out, int out_size, void* d_ws, size_t ws_size,
                              hipStream_t stream) {
  const float* x  = (const float*)d_in[0];
  const float* kr = (const float*)d_in[1];
  const float* ki = (const float*)d_in[2];
  const float* bs = (const float*)d_in[3];
  float* out = (float*)d_out;

  char* p = (char*)d_ws;
  float2* keff2 = (float2*)p; p += (size_t)16 * 255 * 128 * 8;    // 4.18 MB
  short*  zb    = (short*)p;  p += (size_t)64 * 131072 * 2;       // 16.78 MB
  float4* U4    = (float4*)p;                                      // 8.39 MB
  short*  a5    = (short*)p;  p += (size_t)64 * 131072 * 2;       // 16.78 MB (overlays U4+ub)
  short*  ub    = (short*)p;  p += (size_t)64 * 65536 * 2;        // (second half of a5 region)
  short*  t2    = (short*)p;  p += (size_t)196608 * 2;            // 0.39 MB
  short*  t4    = (short*)p;  p += (size_t)196608 * 2;            // 0.39 MB
  short*  t5    = (short*)p;  p += (size_t)131072 * 2;            // 0.26 MB
  float*  v0    = (float*)p;  p += (size_t)2 * 64 * 128 * 4;      // 64 KB
  // Sr/Si (8.33 MB) overlay zb (dead after fold; zb written later by stage2).
  float* Sr = (float*)zb;
  float* Si = Sr + 255 * 255 * 16;
  // ub sits in the upper half of the a5 region: U4 dead after pack_u, ub dead after
  // stage2; stage4 then overwrites the whole region with a5.
  // Fused-front aliasing check: ksum writes Sr/Si (zb region), stage1 writes U4
  // (a5 region), build writes t2/t4/t5 -- all disjoint.

  fused_front<<<12288, 256, 0, stream>>>(kr, ki, Sr, Si, x, U4, t2, t4, t5);
  fold<<<dim3(255, 8), 256, 0, stream>>>(Sr, Si, keff2);
  pack_u<<<dim3(64, 8), 256, 0, stream>>>(U4, ub);
  stage2_mfma<<<dim3(64, 16), 256, 0, stream>>>(ub, t2, keff2, zb);
  stage4_mfma<<<dim3(64, 16), 256, 0, stream>>>(zb, t4, a5, v0);
  stage5_mfma<<<dim3(64, 8), 256, 0, stream>>>(a5, t5, v0, bs, out);
}

// Round 3
// 208.433 us; speedup vs baseline: 1.1863x; 1.0492x over previous
//
#include <hip/hip_runtime.h>
#include <math.h>

// FourierConv via DFT-as-GEMM on the MATRIX pipe.
// out[b,h,w,c] = Re(ifft2(fft2(x,255^2)*Ksum))[h+63,w+63] + bias; Ksum = sum_cout K.
// Half-spectrum q=0..127. Stages 1 (n->q), 2 (m->p), 4 (p->h), 5 (q->w real part) are
// bf16 MFMA GEMMs with SPLIT precision (rel err ~2^-17).
// Operand-fragment rule (verified): both MFMA operands use layout [entity=lane&15][k=quad*8+j];
// first arg's entity -> D row (quad*4+reg), second arg's entity -> D col (lane&15).
// stage4 computes D[q][h] (A=Z, B=T4) so its epilogue emits V directly in stage5's
// A-operand bf16 layout (a5); stage1g likewise emits U directly in stage2's B-operand
// layout (ub), eliminating the pack_u pass. stage5 is a K=256 GEMM + epilogue.
//
// R1: ksum/pack/build are independent; fused into ONE front kernel, block-striped, so the
// HBM/L3 stream (~2.8 TB/s delivered cap; pattern-independent, verified R0 vs R1) overlaps
// the VALU work. R2: stage1 sincos-DFT (heavy dependent VALU chain, didn't hide under the
// stream) replaced by stage1g MFMA GEMM with 4-term split (exact at fp32-accum level);
// pack_u eliminated; fold + stage1g co-scheduled in one mid kernel.

constexpr float PI2_OVER_N = 6.28318530717958647692f / 255.0f;
constexpr float INV_N2 = 1.0f / (255.0f * 255.0f);

typedef __attribute__((ext_vector_type(8))) short bf16x8;   // 8 bf16 = 4 VGPR
typedef __attribute__((ext_vector_type(4))) float f32x4;    // MFMA acc
#define MFMA16 __builtin_amdgcn_mfma_f32_16x16x32_bf16

__device__ __forceinline__ int remap_bc(int xidx) {
  int k = xidx & 7, j = xidx >> 3;
  return ((k >> 1) * 16) + ((k & 1) * 8) + j;   // b = k>>1, c = (k&1)*8 + j
}

__device__ __forceinline__ unsigned short bf16h(float f) {
  unsigned u = __float_as_uint(f);
  return (unsigned short)((u + 0x7FFFu + ((u >> 16) & 1u)) >> 16);
}
__device__ __forceinline__ float bf16f(unsigned short h) {
  return __uint_as_float(((unsigned)h) << 16);
}

// ---------- front bodies ----------

__device__ __forceinline__ void ksum_body(
    int buf, int xb, const float* __restrict__ kr, const float* __restrict__ ki,
    float* __restrict__ Sr, float* __restrict__ Si) {
  const int nrows = 255 * 255 * 16;
  int r = xb * 256 + threadIdx.x;
  if (r >= nrows) return;
  const float* src = (buf == 0) ? kr : ki;
  float* dst = (buf == 0) ? Sr : Si;
  const float4* k4 = (const float4*)(src + (size_t)r * 16);
  float4 a = k4[0], b = k4[1], c = k4[2], d = k4[3];
  dst[r] = a.x + a.y + a.z + a.w + b.x + b.y + b.z + b.w +
           c.x + c.y + c.z + c.w + d.x + d.y + d.z + d.w;
}

// pack_x: xp[bc][plane2: H,L][((mt*16+noct)*16+mcol)*8+j] = split(x[b, m, n, c]),
// m = mt*16+mcol, n = noct*8+j. This is stage1g's A-operand layout (entity=m, k=n).
__device__ __forceinline__ void packx_body(
    int pid, const float* __restrict__ x, short* __restrict__ xp) {
  int bc = pid & 63;                         // b*16 + c
  int mt = pid >> 6;                         // 0..7
  int b = bc >> 4, c = bc & 15;
  int mcol = threadIdx.x & 15;
  int noct = threadIdx.x >> 4;               // 0..15
  int m = mt * 16 + mcol;
  const float* xs = x + ((size_t)(b * 128 + m) * 128 + noct * 8) * 16 + c;
  unsigned short hi[8], lo[8];
#pragma unroll
  for (int j = 0; j < 8; ++j) {
    float v = xs[j * 16];
    hi[j] = bf16h(v);
    lo[j] = bf16h(v - bf16f(hi[j]));
  }
  size_t base = (size_t)bc * 32768 + ((size_t)(mt * 16 + noct) * 16 + mcol) * 8;
  uint4 o;
  o.x = (unsigned)hi[0] | ((unsigned)hi[1] << 16);
  o.y = (unsigned)hi[2] | ((unsigned)hi[3] << 16);
  o.z = (unsigned)hi[4] | ((unsigned)hi[5] << 16);
  o.w = (unsigned)hi[6] | ((unsigned)hi[7] << 16);
  *(uint4*)(xp + base) = o;
  o.x = (unsigned)lo[0] | ((unsigned)lo[1] << 16);
  o.y = (unsigned)lo[2] | ((unsigned)lo[3] << 16);
  o.z = (unsigned)lo[4] | ((unsigned)lo[5] << 16);
  o.w = (unsigned)lo[6] | ((unsigned)lo[7] << 16);
  *(uint4*)(xp + base + 16384) = o;
}

// t1[plane4: cosH,cosL,(-sin)H,(-sin)L][qt8][noct16][qcol16][j8]: E[q][n] = e^{-i th q n}
__device__ __forceinline__ void buildt1_body(int cid, short* __restrict__ t1) {
  int i = cid * 256 + threadIdx.x;           // < 65536
  int plane = i >> 14;
  int r = i & 16383;
  int qt = r >> 11, noct = (r >> 7) & 15, qcol = (r >> 3) & 15, j = r & 7;
  int q = qt * 16 + qcol, n = noct * 8 + j;
  float s, c;
  sincosf(PI2_OVER_N * (float)((q * n) % 255), &s, &c);
  float src = (plane < 2) ? c : -s;
  unsigned short hh = bf16h(src);
  t1[i] = (short)((plane & 1) ? bf16h(src - bf16f(hh)) : hh);
}

// t2[plane6][pt16][moct16][p16][j8]: T2[p][m]=e^{-i th p m}; planes cosH,cosL,TiH,TiL,-TiH,-TiL
// t4[plane6][ht8][poct32][h16][j8]:  T4[h][p]=e^{+i th (h+63)p}; p=255 slot zeroed (K-pad)
// t5[plane4][wt8][koct32][w16][j8]:  T5[w][k]: q=k&127; planes cosH,cosL,(-sin)H,(-sin)L
__device__ __forceinline__ void buildt24_body(
    int cid2, short* __restrict__ t2, short* __restrict__ t4, short* __restrict__ t5) {
  int i = cid2 * 256 + threadIdx.x;          // < 524288
  float s, c;
  if (i < 196608) {
    int plane = i >> 15;
    int r = i & 32767;
    int pt = r >> 11, r2 = r & 2047;
    int moct = r2 >> 7, p = (r2 >> 3) & 15, j = r2 & 7;
    int pg = pt * 16 + p, m = moct * 8 + j;
    int k = ((pg % 255) * m) % 255;
    sincosf(PI2_OVER_N * (float)k, &s, &c);
    float ti = -s;
    float src = (plane < 2) ? c : ((plane < 4) ? ti : -ti);
    unsigned short h = bf16h(src);
    t2[i] = (short)((plane & 1) ? bf16h(src - bf16f(h)) : h);
  } else if (i < 393216) {
    int i2 = i - 196608;
    int plane = i2 >> 15;
    int r = i2 & 32767;
    int ht = r >> 12, r2 = r & 4095;
    int poct = r2 >> 7, h = (r2 >> 3) & 15, j = r2 & 7;
    int p = poct * 8 + j;
    unsigned short val = 0;
    if (p < 255) {
      int hg = ht * 16 + h;
      int k = ((hg + 63) * p) % 255;
      sincosf(PI2_OVER_N * (float)k, &s, &c);
      float src = (plane < 2) ? c : ((plane < 4) ? s : -s);
      unsigned short hh = bf16h(src);
      val = (plane & 1) ? bf16h(src - bf16f(hh)) : hh;
    }
    t4[i2] = (short)val;
  } else {
    int i3 = i - 393216;
    int plane = i3 >> 15;                    // 0..3
    int r = i3 & 32767;
    int wt = r >> 12, r2 = r & 4095;
    int ko = r2 >> 7, wl = (r2 >> 3) & 15, j = r2 & 7;
    int q = (ko * 8 + j) & 127;              // k -> q (both segs identical)
    int ww = wt * 16 + wl;
    sincosf(PI2_OVER_N * (float)(((ww + 63) * q) % 255), &s, &c);
    float src = (plane < 2) ? c : -s;
    unsigned short hh = bf16h(src);
    t5[i3] = (short)((plane & 1) ? bf16h(src - bf16f(hh)) : hh);
  }
}

// fused front: stripe of 4 -> 3 ksum blocks : 1 compute block (pack_x / t1 / t24)
__global__ __launch_bounds__(256) void fused_front(
    const float* __restrict__ kr, const float* __restrict__ ki,
    float* __restrict__ Sr, float* __restrict__ Si,
    const float* __restrict__ x, short* __restrict__ xp,
    short* __restrict__ t1, short* __restrict__ t2,
    short* __restrict__ t4, short* __restrict__ t5) {
  int bid = blockIdx.x;                      // 0..11263
  int d = bid >> 2, r = bid & 3;             // d 0..2815
  if (r == 3) {
    if (d < 512)      packx_body(d, x, xp);
    else if (d < 768) buildt1_body(d - 512, t1);
    else              buildt24_body(d - 768, t2, t4, t5);
  } else {
    int kid = d * 3 + r;
    if (kid < 8192) ksum_body(kid & 1, kid >> 1, kr, ki, Sr, Si);
  }
}

// ---------- mid: fold + stage1g (independent, co-scheduled) ----------

__device__ __forceinline__ void fold_body(
    int fid, const float* __restrict__ Sr, const float* __restrict__ Si,
    float2* __restrict__ keff2) {
  int p = fid % 255;
  int qy = fid / 255;                        // 0..7
  int q = qy * 16 + (threadIdx.x >> 4);
  int c = threadIdx.x & 15;
  int pp = (255 - p) % 255;
  int qq = (255 - q) % 255;
  size_t i0 = (size_t)(p * 255 + q) * 16 + c;
  size_t i1 = (size_t)(pp * 255 + qq) * 16 + c;
  float sr0 = Sr[i0], si0 = Si[i0], sr1 = Sr[i1], si1 = Si[i1];
  float2 v;
  v.x = 0.5f * (sr0 + sr1);
  v.y = 0.5f * (si0 - si1);
  keff2[((size_t)c * 255 + p) * 128 + q] = v;
}

// stage1g: U[m][q] = sum_n x[m,n] E[n][q] as MFMA GEMM (A=xp entity=m, B=t1 entity=q).
// 4-term split (xH+xL)(cH+cL): product exact at fp32-accum level. Epilogue writes ub
// (stage2's B-operand layout) directly: ub[bc][plane4: rH,rL,iH,iL][qt*2048+moct*128+qcol*8+j].
__device__ __forceinline__ void s1g_body(
    int gid, const short* __restrict__ xp, const short* __restrict__ t1,
    short* __restrict__ ub) {
  int bc = gid & 63;
  int mt = gid >> 6;                         // 0..7
  int w = threadIdx.x >> 6;                  // qt pair
  int lane = threadIdx.x & 63;
  int quad = lane >> 4, col = lane & 15;
  f32x4 ur[2] = {{0,0,0,0},{0,0,0,0}};
  f32x4 ui[2] = {{0,0,0,0},{0,0,0,0}};
  const short* xb = xp + (size_t)bc * 32768;
#pragma unroll
  for (int ko = 0; ko < 4; ++ko) {
    int noct = ko * 4 + quad;
    const short* pa = xb + ((size_t)(mt * 16 + noct) * 16 + col) * 8;
    bf16x8 xh = *(const bf16x8*)(pa);
    bf16x8 xl = *(const bf16x8*)(pa + 16384);
#pragma unroll
    for (int qq = 0; qq < 2; ++qq) {
      int qt = w * 2 + qq;
      const short* pb = t1 + ((size_t)(qt * 16 + noct) * 16 + col) * 8;
      bf16x8 ch = *(const bf16x8*)(pb);
      bf16x8 cl = *(const bf16x8*)(pb + 16384);
      bf16x8 nh = *(const bf16x8*)(pb + 2 * 16384);
      bf16x8 nl = *(const bf16x8*)(pb + 3 * 16384);
      ur[qq] = MFMA16(xh, ch, ur[qq], 0, 0, 0);
      ur[qq] = MFMA16(xh, cl, ur[qq], 0, 0, 0);
      ur[qq] = MFMA16(xl, ch, ur[qq], 0, 0, 0);
      ur[qq] = MFMA16(xl, cl, ur[qq], 0, 0, 0);
      ui[qq] = MFMA16(xh, nh, ui[qq], 0, 0, 0);
      ui[qq] = MFMA16(xh, nl, ui[qq], 0, 0, 0);
      ui[qq] = MFMA16(xl, nh, ui[qq], 0, 0, 0);
      ui[qq] = MFMA16(xl, nl, ui[qq], 0, 0, 0);
    }
  }
  // D row = m = mt*16 + quad*4 + r  (j-contiguous per quad-half)
  int moct = mt * 2 + (quad >> 1);
  int j0 = (quad & 1) * 4;
#pragma unroll
  for (int qq = 0; qq < 2; ++qq) {
    int qt = w * 2 + qq;
    unsigned short rh[4], rl[4], ih[4], il[4];
#pragma unroll
    for (int r = 0; r < 4; ++r) {
      rh[r] = bf16h(ur[qq][r]); rl[r] = bf16h(ur[qq][r] - bf16f(rh[r]));
      ih[r] = bf16h(ui[qq][r]); il[r] = bf16h(ui[qq][r] - bf16f(ih[r]));
    }
    size_t base = (size_t)bc * 65536 + (size_t)qt * 2048 + (size_t)moct * 128 +
                  (size_t)col * 8 + j0;
    uint2 o;
    o.x = (unsigned)rh[0] | ((unsigned)rh[1] << 16);
    o.y = (unsigned)rh[2] | ((unsigned)rh[3] << 16);
    *(uint2*)(ub + base) = o;
    o.x = (unsigned)rl[0] | ((unsigned)rl[1] << 16);
    o.y = (unsigned)rl[2] | ((unsigned)rl[3] << 16);
    *(uint2*)(ub + base + 16384) = o;
    o.x = (unsigned)ih[0] | ((unsigned)ih[1] << 16);
    o.y = (unsigned)ih[2] | ((unsigned)ih[3] << 16);
    *(uint2*)(ub + base + 2 * 16384) = o;
    o.x = (unsigned)il[0] | ((unsigned)il[1] << 16);
    o.y = (unsigned)il[2] | ((unsigned)il[3] << 16);
    *(uint2*)(ub + base + 3 * 16384) = o;
  }
}

// stripe of 5: 4 fold blocks : 1 stage1g block
__global__ __launch_bounds__(256) void mid(
    const float* __restrict__ Sr, const float* __restrict__ Si,
    float2* __restrict__ keff2,
    const short* __restrict__ xp, const short* __restrict__ t1,
    short* __restrict__ ub) {
  int bid = blockIdx.x;                      // 0..2559
  int d = bid / 5, r = bid - d * 5;
  if (r == 4) {
    s1g_body(d, xp, t1, ub);                 // d 0..511
  } else {
    int fid = d * 4 + r;
    if (fid < 2040) fold_body(fid, Sr, Si, keff2);
  }
}

// ---------- stage2_mfma: X[p][q] = sum_m T2[p][m] U[m][q]; Z = Keff*X -> zb bf16 splits ----------
// zb[bc][plane4][qt8][poct32][q16][j8] (p in k-position for stage4's A side).
__global__ __launch_bounds__(256) void stage2_mfma(
    const short* __restrict__ ub, const short* __restrict__ t2,
    const float2* __restrict__ keff2, short* __restrict__ zb) {
  int bc = remap_bc(blockIdx.x);
  int c = bc & 15;
  int w = threadIdx.x >> 6;
  int lane = threadIdx.x & 63;
  int quad = lane >> 4, col = lane & 15;
  int pt = blockIdx.y;                       // 0..15
  int qh = w;                                // 0..3 -> 2 qt each
  f32x4 accr[2] = {{0,0,0,0},{0,0,0,0}};
  f32x4 acci[2] = {{0,0,0,0},{0,0,0,0}};
  const short* ubase = ub + (size_t)bc * 65536;
#pragma unroll
  for (int ko = 0; ko < 4; ++ko) {
    int moct = ko * 4 + quad;
    const short* ta = t2 + ((size_t)(pt * 16 + moct) * 16 + col) * 8;
    bf16x8 arh = *(const bf16x8*)(ta);
    bf16x8 arl = *(const bf16x8*)(ta + 32768);
    bf16x8 aih = *(const bf16x8*)(ta + 2 * 32768);
    bf16x8 ail = *(const bf16x8*)(ta + 3 * 32768);
    bf16x8 anh = *(const bf16x8*)(ta + 4 * 32768);
    bf16x8 anl = *(const bf16x8*)(ta + 5 * 32768);
#pragma unroll
    for (int qq = 0; qq < 2; ++qq) {
      int qt = qh * 2 + qq;
      const short* tb = ubase + ((size_t)(qt * 16 + moct) * 16 + col) * 8;
      bf16x8 brh = *(const bf16x8*)(tb);
      bf16x8 brl = *(const bf16x8*)(tb + 16384);
      bf16x8 bih = *(const bf16x8*)(tb + 2 * 16384);
      bf16x8 bil = *(const bf16x8*)(tb + 3 * 16384);
      accr[qq] = MFMA16(arh, brh, accr[qq], 0, 0, 0);
      accr[qq] = MFMA16(arh, brl, accr[qq], 0, 0, 0);
      accr[qq] = MFMA16(arl, brh, accr[qq], 0, 0, 0);
      accr[qq] = MFMA16(anh, bih, accr[qq], 0, 0, 0);
      accr[qq] = MFMA16(anh, bil, accr[qq], 0, 0, 0);
      accr[qq] = MFMA16(anl, bih, accr[qq], 0, 0, 0);
      acci[qq] = MFMA16(arh, bih, acci[qq], 0, 0, 0);
      acci[qq] = MFMA16(arh, bil, acci[qq], 0, 0, 0);
      acci[qq] = MFMA16(arl, bih, acci[qq], 0, 0, 0);
      acci[qq] = MFMA16(aih, brh, acci[qq], 0, 0, 0);
      acci[qq] = MFMA16(aih, brl, acci[qq], 0, 0, 0);
      acci[qq] = MFMA16(ail, brh, acci[qq], 0, 0, 0);
    }
  }
  int poct = pt * 2 + (quad >> 1);
  size_t joff = (size_t)col * 8 + (quad & 1) * 4;
#pragma unroll
  for (int qq = 0; qq < 2; ++qq) {
    int qt = qh * 2 + qq;
    int qg = qt * 16 + col;
    float zr[4], zi[4];
#pragma unroll
    for (int r = 0; r < 4; ++r) {
      int pg = pt * 16 + quad * 4 + r;
      int pgc = pg < 255 ? pg : 254;         // keff in-bounds; p=255 slot killed by zero B in t4 k-pad
      float2 k = keff2[((size_t)c * 255 + pgc) * 128 + qg];
      float xr = accr[qq][r], xi = acci[qq][r];
      zr[r] = k.x * xr - k.y * xi;
      zi[r] = k.x * xi + k.y * xr;
    }
    unsigned short hr[4], lr[4], hi_[4], li[4];
#pragma unroll
    for (int r = 0; r < 4; ++r) {
      hr[r] = bf16h(zr[r]);  lr[r] = bf16h(zr[r] - bf16f(hr[r]));
      hi_[r] = bf16h(zi[r]); li[r] = bf16h(zi[r] - bf16f(hi_[r]));
    }
    size_t base = (size_t)bc * 131072 + (size_t)qt * 4096 + (size_t)poct * 128 + joff;
    uint2 o;
    o.x = (unsigned)hr[0] | ((unsigned)hr[1] << 16);
    o.y = (unsigned)hr[2] | ((unsigned)hr[3] << 16);
    *(uint2*)(zb + base) = o;
    o.x = (unsigned)lr[0] | ((unsigned)lr[1] << 16);
    o.y = (unsigned)lr[2] | ((unsigned)lr[3] << 16);
    *(uint2*)(zb + base + 32768) = o;
    o.x = (unsigned)hi_[0] | ((unsigned)hi_[1] << 16);
    o.y = (unsigned)hi_[2] | ((unsigned)hi_[3] << 16);
    *(uint2*)(zb + base + 2 * 32768) = o;
    o.x = (unsigned)li[0] | ((unsigned)li[1] << 16);
    o.y = (unsigned)li[2] | ((unsigned)li[3] << 16);
    *(uint2*)(zb + base + 3 * 32768) = o;
  }
}

// ---------- stage4_mfma (operands SWAPPED: A=Z -> D rows=q, B=T4 -> D cols=h) ----------
// Epilogue writes V bf16 hi/lo splits directly into stage5's A-operand layout:
// a5[bc][plane4: VrH,VrL,ViH,ViL][ht8][koct32][h16][j8], k = kseg*128 + q.
// Also v0[kseg*64+bc][h] = Vr_seg[h][q=0] (fp32) for stage5's half-term fix.
__global__ __launch_bounds__(256) void stage4_mfma(
    const short* __restrict__ zb, const short* __restrict__ t4,
    short* __restrict__ a5, float* __restrict__ v0) {
  int bc = remap_bc(blockIdx.x);
  int w = threadIdx.x >> 6;
  int lane = threadIdx.x & 63;
  int quad = lane >> 4, col = lane & 15;
  int u = blockIdx.y * 4 + w;                // 0..63
  int qt = u >> 3;                           // 0..7 (q-tile -> D rows)
  int kseg = (u >> 2) & 1;                   // p-segment
  int htp = u & 3;                           // 2 h-tiles: htp*2, htp*2+1
  f32x4 accr[2] = {{0,0,0,0},{0,0,0,0}};
  f32x4 acci[2] = {{0,0,0,0},{0,0,0,0}};
  const short* zbase = zb + (size_t)bc * 131072;
#pragma unroll
  for (int ko = 0; ko < 4; ++ko) {
    int poct = kseg * 16 + ko * 4 + quad;
    const short* tz = zbase + ((size_t)(qt * 32 + poct) * 16 + col) * 8;
    bf16x8 zrh = *(const bf16x8*)(tz);
    bf16x8 zrl = *(const bf16x8*)(tz + 32768);
    bf16x8 zih = *(const bf16x8*)(tz + 2 * 32768);
    bf16x8 zil = *(const bf16x8*)(tz + 3 * 32768);
#pragma unroll
    for (int t = 0; t < 2; ++t) {
      int ht = htp * 2 + t;
      const short* ta = t4 + ((size_t)(ht * 32 + poct) * 16 + col) * 8;
      bf16x8 trh = *(const bf16x8*)(ta);
      bf16x8 trl = *(const bf16x8*)(ta + 32768);
      bf16x8 tih = *(const bf16x8*)(ta + 2 * 32768);
      bf16x8 til = *(const bf16x8*)(ta + 3 * 32768);
      bf16x8 tnh = *(const bf16x8*)(ta + 4 * 32768);
      bf16x8 tnl = *(const bf16x8*)(ta + 5 * 32768);
      // Vr = Zr*Tr + Zi*(-Ti)
      accr[t] = MFMA16(zrh, trh, accr[t], 0, 0, 0);
      accr[t] = MFMA16(zrh, trl, accr[t], 0, 0, 0);
      accr[t] = MFMA16(zrl, trh, accr[t], 0, 0, 0);
      accr[t] = MFMA16(zih, tnh, accr[t], 0, 0, 0);
      accr[t] = MFMA16(zih, tnl, accr[t], 0, 0, 0);
      accr[t] = MFMA16(zil, tnh, accr[t], 0, 0, 0);
      // Vi = Zi*Tr + Zr*Ti
      acci[t] = MFMA16(zih, trh, acci[t], 0, 0, 0);
      acci[t] = MFMA16(zih, trl, acci[t], 0, 0, 0);
      acci[t] = MFMA16(zil, trh, acci[t], 0, 0, 0);
      acci[t] = MFMA16(zrh, tih, acci[t], 0, 0, 0);
      acci[t] = MFMA16(zrh, til, acci[t], 0, 0, 0);
      acci[t] = MFMA16(zrl, tih, acci[t], 0, 0, 0);
    }
  }
  // lane rows: q = qt*16 + quad*4 + r  ->  k = kseg*128 + q (contiguous in r)
  int ko_s = kseg * 16 + qt * 2 + (quad >> 1);
  int j0 = (quad & 1) * 4;
#pragma unroll
  for (int t = 0; t < 2; ++t) {
    int ht = htp * 2 + t;
    unsigned short vh[4], vl[4], wh[4], wl2[4];
#pragma unroll
    for (int r = 0; r < 4; ++r) {
      vh[r] = bf16h(accr[t][r]);  vl[r] = bf16h(accr[t][r] - bf16f(vh[r]));
      wh[r] = bf16h(acci[t][r]);  wl2[r] = bf16h(acci[t][r] - bf16f(wh[r]));
    }
    size_t base = (((size_t)(bc * 4) * 8 + ht) * 32 + ko_s) * 128 + (size_t)col * 8 + j0;
    uint2 o;
    o.x = (unsigned)vh[0] | ((unsigned)vh[1] << 16);
    o.y = (unsigned)vh[2] | ((unsigned)vh[3] << 16);
    *(uint2*)(a5 + base) = o;
    o.x = (unsigned)vl[0] | ((unsigned)vl[1] << 16);
    o.y = (unsigned)vl[2] | ((unsigned)vl[3] << 16);
    *(uint2*)(a5 + base + 32768) = o;
    o.x = (unsigned)wh[0] | ((unsigned)wh[1] << 16);
    o.y = (unsigned)wh[2] | ((unsigned)wh[3] << 16);
    *(uint2*)(a5 + base + 2 * 32768) = o;
    o.x = (unsigned)wl2[0] | ((unsigned)wl2[1] << 16);
    o.y = (unsigned)wl2[2] | ((unsigned)wl2[3] << 16);
    *(uint2*)(a5 + base + 3 * 32768) = o;
    if (qt == 0 && quad == 0)                // row 0 => q = 0
      v0[(size_t)(kseg * 64 + bc) * 128 + ht * 16 + col] = accr[t][0];
  }
}

// ---------- stage5_mfma: O[h][w] = sum_{k=0..255} (Vr*cos + Vi*(-sin)) ; out = (2O - v0)*1/N^2 + bias ----------
// A = a5 (h -> D rows), B = t5 (w -> D cols). K=256 folds both p-segments (sum free in acc).
__global__ __launch_bounds__(256) void stage5_mfma(
    const short* __restrict__ a5, const short* __restrict__ t5,
    const float* __restrict__ v0, const float* __restrict__ bias,
    float* __restrict__ out) {
  int bc = remap_bc(blockIdx.x);
  int w = threadIdx.x >> 6;
  int lane = threadIdx.x & 63;
  int quad = lane >> 4, col = lane & 15;
  int u = blockIdx.y * 4 + w;                // 0..31
  int ht = u >> 2;                           // 0..7
  int wtp = u & 3;                           // 2 w-tiles
  f32x4 acc[2] = {{0,0,0,0},{0,0,0,0}};
  const short* abase = a5 + (size_t)bc * 131072;
#pragma unroll
  for (int kc = 0; kc < 8; ++kc) {
    int koq = kc * 4 + quad;                 // k-oct 0..31
    const short* pa = abase + ((size_t)(ht * 32 + koq) * 16 + col) * 8;
    bf16x8 vrh = *(const bf16x8*)(pa);
    bf16x8 vrl = *(const bf16x8*)(pa + 32768);
    bf16x8 vih = *(const bf16x8*)(pa + 2 * 32768);
    bf16x8 vil = *(const bf16x8*)(pa + 3 * 32768);
#pragma unroll
    for (int t = 0; t < 2; ++t) {
      int wt = wtp * 2 + t;
      const short* pb = t5 + ((size_t)(wt * 32 + koq) * 16 + col) * 8;
      bf16x8 tch = *(const bf16x8*)(pb);
      bf16x8 tcl = *(const bf16x8*)(pb + 32768);
      bf16x8 tnh = *(const bf16x8*)(pb + 2 * 32768);
      bf16x8 tnl = *(const bf16x8*)(pb + 3 * 32768);
      acc[t] = MFMA16(vrh, tch, acc[t], 0, 0, 0);
      acc[t] = MFMA16(vrh, tcl, acc[t], 0, 0, 0);
      acc[t] = MFMA16(vrl, tch, acc[t], 0, 0, 0);
      acc[t] = MFMA16(vih, tnh, acc[t], 0, 0, 0);
      acc[t] = MFMA16(vih, tnl, acc[t], 0, 0, 0);
      acc[t] = MFMA16(vil, tnh, acc[t], 0, 0, 0);
    }
  }
  int b = bc >> 4, c = bc & 15;
  float bb = bias[c];
  float v0t[4];
#pragma unroll
  for (int r = 0; r < 4; ++r) {
    int h = ht * 16 + quad * 4 + r;
    v0t[r] = v0[(size_t)bc * 128 + h] + v0[(size_t)(64 + bc) * 128 + h];
  }
#pragma unroll
  for (int t = 0; t < 2; ++t) {
    int ww = (wtp * 2 + t) * 16 + col;
#pragma unroll
    for (int r = 0; r < 4; ++r) {
      int h = ht * 16 + quad * 4 + r;
      out[((size_t)(b * 128 + h) * 128 + ww) * 16 + c] =
          (2.0f * acc[t][r] - v0t[r]) * INV_N2 + bb;
    }
  }
}

extern "C" void kernel_launch(void* const* d_in, const int* in_sizes, int n_in,
                              void* d_out, int out_size, void* d_ws, size_t ws_size,
                              hipStream_t stream) {
  const float* x  = (const float*)d_in[0];
  const float* kr = (const float*)d_in[1];
  const float* ki = (const float*)d_in[2];
  const float* bs = (const float*)d_in[3];
  float* out = (float*)d_out;

  char* p = (char*)d_ws;
  float2* keff2 = (float2*)p; p += (size_t)16 * 255 * 128 * 8;    // 4.18 MB
  short*  zb    = (short*)p;  p += (size_t)64 * 131072 * 2;       // 16.78 MB
  char*   a5reg = p;
  short*  a5    = (short*)p;  p += (size_t)64 * 131072 * 2;       // 16.78 MB
  short*  ub    = (short*)p;  p += (size_t)64 * 65536 * 2;        // 8.39 MB
  short*  t2    = (short*)p;  p += (size_t)196608 * 2;            // 0.39 MB
  short*  t4    = (short*)p;  p += (size_t)196608 * 2;            // 0.39 MB
  short*  t5    = (short*)p;  p += (size_t)131072 * 2;            // 0.26 MB
  float*  v0    = (float*)p;  p += (size_t)2 * 64 * 128 * 4;      // 64 KB
  // Sr/Si (8.33 MB) overlay zb (dead after mid's fold; zb written later by stage2).
  float* Sr = (float*)zb;
  float* Si = Sr + 255 * 255 * 16;
  // xp (4.19 MB) and t1 (128 KB) overlay the a5 region, which is first written by
  // stage4 (after mid/stage2 have consumed xp/t1). xp at +0; t1 at +6 MB (in the gap).
  short* xp = (short*)a5reg;
  short* t1 = (short*)(a5reg + 6 * 1024 * 1024);

  fused_front<<<11264, 256, 0, stream>>>(kr, ki, Sr, Si, x, xp, t1, t2, t4, t5);
  mid<<<2560, 256, 0, stream>>>(Sr, Si, keff2, xp, t1, ub);
  stage2_mfma<<<dim3(64, 16), 256, 0, stream>>>(ub, t2, keff2, zb);
  stage4_mfma<<<dim3(64, 16), 256, 0, stream>>>(zb, t4, a5, v0);
  stage5_mfma<<<dim3(64, 8), 256, 0, stream>>>(a5, t5, v0, bs, out);
}